// Round 10
// baseline (152.992 us; speedup 1.0000x reference)
//
#include <hip/hip_runtime.h>

#define U_CNT 16384
#define I_CNT 8192
#define DIM 64
#define BAND 16                   // rows per band (per block per step)
#define CHUNK 256                 // cols owned by one block (fixed)
#define NSTEP 32                  // bands per group sweep
#define LDS_STRIDE 68             // floats; 68 % 32 == 4 -> 2-way conflicts only (free)
#define NEG_LOG2E (-1.4426950408889634f)

typedef __bf16 bf16x8 __attribute__((ext_vector_type(8)));
typedef float f32x4 __attribute__((ext_vector_type(4)));
typedef short short8 __attribute__((ext_vector_type(8)));

__device__ __forceinline__ unsigned short f32_to_bf16_rtn(float f) {
    unsigned int b = __float_as_uint(f);
    b += 0x7fffu + ((b >> 16) & 1u);
    return (unsigned short)(b >> 16);
}

// One wave per user: binary-search segment bounds in sorted seg_ids (no prep
// kernel / bounds array), sum Q2 rows (lane = dim), scale by rsqrt(count),
// add P, write bf16 A-matrix. Gather unrolled x4 to keep 4 row-loads in
// flight. The ~40 dependent binary-search loads hide under cross-wave TLP.
__global__ __launch_bounds__(256) void pfull_kernel(
    const float* __restrict__ Q2, const float* __restrict__ P,
    const int* __restrict__ items, const int* __restrict__ segs,
    int nnz, unsigned short* __restrict__ Pbf)
{
    int u = (blockIdx.x * 256 + threadIdx.x) >> 6;
    int lane = threadIdx.x & 63;
    if (u >= U_CNT) return;

    int lo = 0, hi = nnz;
    while (lo < hi) { int m = (lo + hi) >> 1; if (segs[m] < u) lo = m + 1; else hi = m; }
    int start = lo;
    hi = nnz;
    while (lo < hi) { int m = (lo + hi) >> 1; if (segs[m] <= u) lo = m + 1; else hi = m; }
    int end = lo;

    float s = 0.f;
    int j = start;
    for (; j + 3 < end; j += 4) {
        int i0 = items[j], i1 = items[j + 1], i2 = items[j + 2], i3 = items[j + 3];
        float v0 = Q2[i0 * DIM + lane];
        float v1 = Q2[i1 * DIM + lane];
        float v2 = Q2[i2 * DIM + lane];
        float v3 = Q2[i3 * DIM + lane];
        s += (v0 + v1) + (v2 + v3);
    }
    for (; j < end; ++j) s += Q2[items[j] * DIM + lane];

    int cnt = end - start;              // guaranteed >= 1
    float val = s * rsqrtf((float)cnt) + P[u * DIM + lane];
    Pbf[u * DIM + lane] = f32_to_bf16_rtn(val);
}

// Coordinated-window GEMM + sigmoid (the 130.6us champion structure), with
// Q1 consumed DIRECTLY as f32 and converted to bf16 fragments in-register
// (one-time, ~64 cvt/thread) — the prep kernel and Q1bf buffer are gone.
// Grid = 1024 blocks (32 groups x 32 members). Block b: member = b&31 owns
// fixed cols [member*256, +256); group = b>>5. Step s: band (group + s*32).
// At step s the whole GPU writes rows [s*512, +512) = a contiguous 16 MB
// window sweeping linearly (fill-kernel shape). B fragments + bi register-
// resident; per step only the 2-instr A fragment + bu reload. Epilogue:
// sigmoid in acc layout, per-wave-private LDS transpose, 4 nontemporal
// 256B-per-row store instructions.
__global__ __launch_bounds__(256) void gemm_sig_kernel(
    const unsigned short* __restrict__ Abf, const float* __restrict__ Q1,
    const float* __restrict__ bu, const float* __restrict__ bi,
    float* __restrict__ out)
{
    const int lane = threadIdx.x & 63;
    const int wid  = threadIdx.x >> 6;      // 0..3: 64-col sub-band within chunk
    const int r = lane & 15, g = lane >> 4;
    const int member = blockIdx.x & 31;     // fixed col chunk
    const int group  = blockIdx.x >> 5;     // 0..31
    const int col0 = member * CHUNK + wid * 64;

    __shared__ float lds_all[4][BAND * LDS_STRIDE];
    float* lds = lds_all[wid];              // per-wave private region

    // B fragments + bi: loaded ONCE from f32 Q1, converted in-register,
    // register-resident for the whole kernel.
    bf16x8 b[4][2];
    float bi_f[4];
#pragma unroll
    for (int nf = 0; nf < 4; ++nf) {
        bi_f[nf] = bi[col0 + nf * 16 + r] + 0.05f;   // fold the +0.05 here
#pragma unroll
        for (int ks = 0; ks < 2; ++ks) {
            const float* src = &Q1[(col0 + nf * 16 + r) * DIM + ks * 32 + g * 8];
            f32x4 vlo = *reinterpret_cast<const f32x4*>(src);
            f32x4 vhi = *reinterpret_cast<const f32x4*>(src + 4);
            short8 t;
#pragma unroll
            for (int e = 0; e < 4; ++e) {
                t[e]     = (short)f32_to_bf16_rtn(vlo[e]);
                t[e + 4] = (short)f32_to_bf16_rtn(vhi[e]);
            }
            b[nf][ks] = *reinterpret_cast<bf16x8*>(&t);
        }
    }

    for (int s = 0; s < NSTEP; ++s) {
        const int band = (group + s * 32) * BAND;

        // A fragment for this band (rows band..band+15), both K-steps.
        bf16x8 a[2];
#pragma unroll
        for (int ks = 0; ks < 2; ++ks)
            a[ks] = *reinterpret_cast<const bf16x8*>(
                &Abf[(band + r) * DIM + ks * 32 + g * 8]);

        float bu_g[4];
#pragma unroll
        for (int j = 0; j < 4; ++j) bu_g[j] = bu[band + g * 4 + j];

        f32x4 acc[4] = {};
#pragma unroll
        for (int ks = 0; ks < 2; ++ks)
#pragma unroll
            for (int nf = 0; nf < 4; ++nf)
                acc[nf] = __builtin_amdgcn_mfma_f32_16x16x32_bf16(
                    a[ks], b[nf][ks], acc[nf], 0, 0, 0);

        // Sigmoid in acc layout (row = g*4+j, col = nf*16+r), then transpose
        // through per-wave LDS.
#pragma unroll
        for (int nf = 0; nf < 4; ++nf)
#pragma unroll
            for (int j = 0; j < 4; ++j) {
                float x = (acc[nf][j] + bu_g[j] + bi_f[nf]) * NEG_LOG2E;
                float e = __builtin_amdgcn_exp2f(x);
                float v = 5.f * __builtin_amdgcn_rcpf(1.f + e);
                lds[(g * 4 + j) * LDS_STRIDE + nf * 16 + r] = v;
            }

        // Store: instr i covers rows i*4..i*4+3 (g picks row, r picks 16B
        // slot): 256B contiguous per row, full cache lines, nontemporal.
#pragma unroll
        for (int i = 0; i < 4; ++i) {
            const int row = i * 4 + g;
            f32x4 v = *reinterpret_cast<const f32x4*>(&lds[row * LDS_STRIDE + r * 4]);
            __builtin_nontemporal_store(v, reinterpret_cast<f32x4*>(
                &out[(size_t)(band + row) * I_CNT + col0 + r * 4]));
        }
    }
}

extern "C" void kernel_launch(void* const* d_in, const int* in_sizes, int n_in,
                              void* d_out, int out_size, void* d_ws, size_t ws_size,
                              hipStream_t stream)
{
    const float* Q1 = (const float*)d_in[0];
    const float* Q2 = (const float*)d_in[1];
    const float* P  = (const float*)d_in[2];
    const float* bu = (const float*)d_in[3];
    const float* bi = (const float*)d_in[4];
    const int* items = (const int*)d_in[5];
    const int* segs  = (const int*)d_in[6];
    const int nnz = in_sizes[5];

    unsigned short* Pbf = (unsigned short*)d_ws;             // 2 MB

    pfull_kernel<<<U_CNT / 4, 256, 0, stream>>>(Q2, P, items, segs, nnz, Pbf);
    // 32 groups x 32 members = 1024 blocks; each block sweeps NSTEP=32 bands.
    gemm_sig_kernel<<<32 * 32, 256, 0, stream>>>(Pbf, Q1, bu, bi, (float*)d_out);
}

// Round 11
// 133.129 us; speedup vs baseline: 1.1492x; 1.1492x over previous
//
#include <hip/hip_runtime.h>

#define U_CNT 16384
#define I_CNT 8192
#define DIM 64
#define BAND 16                   // rows per band (per block per step)
#define CHUNK 256                 // cols owned by one block (fixed)
#define NSTEP 32                  // bands per group sweep
#define LDS_STRIDE 68             // floats; 68 % 32 == 4 -> 2-way conflicts only (free)
#define NEG_LOG2E (-1.4426950408889634f)

typedef __bf16 bf16x8 __attribute__((ext_vector_type(8)));
typedef float f32x4 __attribute__((ext_vector_type(4)));

__device__ __forceinline__ unsigned short f32_to_bf16_rtn(float f) {
    unsigned int b = __float_as_uint(f);
    b += 0x7fffu + ((b >> 16) & 1u);
    return (unsigned short)(b >> 16);
}

// Prep: blocks [0, 2048) convert Q1 -> bf16; blocks [2048, ...) scan seg_ids
// for segment boundaries (every user has >=1 item -> every bounds[u] written
// exactly once; bounds[U_CNT] = nnz).
__global__ __launch_bounds__(256) void prep_kernel(
    const float* __restrict__ Q1, unsigned short* __restrict__ Q1bf,
    const int* __restrict__ segs, int nnz, int* __restrict__ bounds)
{
    if (blockIdx.x < 2048) {
        int i = blockIdx.x * 256 + threadIdx.x;   // covers I_CNT*DIM = 524288
        Q1bf[i] = f32_to_bf16_rtn(Q1[i]);
    } else {
        int i = (blockIdx.x - 2048) * 256 + threadIdx.x;
        if (i >= nnz) return;
        if (i == 0) bounds[segs[0]] = 0;
        else if (segs[i] != segs[i - 1]) bounds[segs[i]] = i;
        if (i == nnz - 1) bounds[U_CNT] = nnz;
    }
}

// One BLOCK per user: 4 waves split the user's item range (quarters the
// serial latency chain AND the ragged-degree imbalance vs 1-wave/user at
// identical L2 traffic), partial sums combined through LDS; wave 0
// finalizes (rsqrt(count), +P, bf16 convert, coalesced 128B row store).
__global__ __launch_bounds__(256) void pfull_kernel(
    const float* __restrict__ Q2, const float* __restrict__ P,
    const int* __restrict__ items, const int* __restrict__ bounds,
    unsigned short* __restrict__ Pbf)
{
    const int u = blockIdx.x;
    const int lane = threadIdx.x & 63;
    const int w = threadIdx.x >> 6;
    __shared__ float part[4][64];

    const int start = bounds[u];
    const int end   = bounds[u + 1];
    const int cnt   = end - start;          // guaranteed >= 1
    const int per   = (cnt + 3) >> 2;
    const int s0 = start + w * per;
    const int s1 = min(s0 + per, end);

    float s = 0.f;
    int j = s0;
    for (; j + 3 < s1; j += 4) {
        int i0 = items[j], i1 = items[j + 1], i2 = items[j + 2], i3 = items[j + 3];
        float v0 = Q2[i0 * DIM + lane];
        float v1 = Q2[i1 * DIM + lane];
        float v2 = Q2[i2 * DIM + lane];
        float v3 = Q2[i3 * DIM + lane];
        s += (v0 + v1) + (v2 + v3);
    }
    for (; j < s1; ++j) s += Q2[items[j] * DIM + lane];

    part[w][lane] = s;
    __syncthreads();
    if (threadIdx.x < 64) {
        float tot = (part[0][lane] + part[1][lane]) + (part[2][lane] + part[3][lane]);
        float val = tot * rsqrtf((float)cnt) + P[u * DIM + lane];
        Pbf[u * DIM + lane] = f32_to_bf16_rtn(val);
    }
}

// Coordinated-window GEMM + sigmoid — EXACT 130.6us champion (round 9).
// Grid = 1024 blocks (32 groups x 32 members). Block b: member = b&31 owns
// fixed cols [member*256, +256); group = b>>5. Step s: band (group + s*32).
// At step s the whole GPU writes rows [s*512, +512) = a contiguous 16 MB
// window sweeping linearly (fill-kernel shape) instead of 16K scattered
// 1KB-granule streams over 536 MB. B fragments + bi register-resident
// (loaded once from bf16 Q1bf); per step only the 2-instr A fragment + bu
// reload. Epilogue: sigmoid in acc layout, per-wave-private LDS transpose,
// 4 nontemporal 256B-per-row store instructions.
__global__ __launch_bounds__(256) void gemm_sig_kernel(
    const unsigned short* __restrict__ Abf, const unsigned short* __restrict__ Bbf,
    const float* __restrict__ bu, const float* __restrict__ bi,
    float* __restrict__ out)
{
    const int lane = threadIdx.x & 63;
    const int wid  = threadIdx.x >> 6;      // 0..3: 64-col sub-band within chunk
    const int r = lane & 15, g = lane >> 4;
    const int member = blockIdx.x & 31;     // fixed col chunk
    const int group  = blockIdx.x >> 5;     // 0..31
    const int col0 = member * CHUNK + wid * 64;

    __shared__ float lds_all[4][BAND * LDS_STRIDE];
    float* lds = lds_all[wid];              // per-wave private region

    // B fragments + bi: loaded ONCE, register-resident for the whole kernel.
    bf16x8 b[4][2];
    float bi_f[4];
#pragma unroll
    for (int nf = 0; nf < 4; ++nf) {
        bi_f[nf] = bi[col0 + nf * 16 + r] + 0.05f;   // fold the +0.05 here
#pragma unroll
        for (int ks = 0; ks < 2; ++ks)
            b[nf][ks] = *reinterpret_cast<const bf16x8*>(
                &Bbf[(col0 + nf * 16 + r) * DIM + ks * 32 + g * 8]);
    }

    for (int s = 0; s < NSTEP; ++s) {
        const int band = (group + s * 32) * BAND;

        // A fragment for this band (rows band..band+15), both K-steps.
        bf16x8 a[2];
#pragma unroll
        for (int ks = 0; ks < 2; ++ks)
            a[ks] = *reinterpret_cast<const bf16x8*>(
                &Abf[(band + r) * DIM + ks * 32 + g * 8]);

        float bu_g[4];
#pragma unroll
        for (int j = 0; j < 4; ++j) bu_g[j] = bu[band + g * 4 + j];

        f32x4 acc[4] = {};
#pragma unroll
        for (int ks = 0; ks < 2; ++ks)
#pragma unroll
            for (int nf = 0; nf < 4; ++nf)
                acc[nf] = __builtin_amdgcn_mfma_f32_16x16x32_bf16(
                    a[ks], b[nf][ks], acc[nf], 0, 0, 0);

        // Sigmoid in acc layout (row = g*4+j, col = nf*16+r), then transpose
        // through per-wave LDS.
#pragma unroll
        for (int nf = 0; nf < 4; ++nf)
#pragma unroll
            for (int j = 0; j < 4; ++j) {
                float x = (acc[nf][j] + bu_g[j] + bi_f[nf]) * NEG_LOG2E;
                float e = __builtin_amdgcn_exp2f(x);
                float v = 5.f * __builtin_amdgcn_rcpf(1.f + e);
                lds[(g * 4 + j) * LDS_STRIDE + nf * 16 + r] = v;
            }

        // Store: instr i covers rows i*4..i*4+3 (g picks row, r picks 16B
        // slot): 256B contiguous per row, full cache lines, nontemporal.
#pragma unroll
        for (int i = 0; i < 4; ++i) {
            const int row = i * 4 + g;
            f32x4 v = *reinterpret_cast<const f32x4*>(&lds[row * LDS_STRIDE + r * 4]);
            __builtin_nontemporal_store(v, reinterpret_cast<f32x4*>(
                &out[(size_t)(band + row) * I_CNT + col0 + r * 4]));
        }
    }
}

extern "C" void kernel_launch(void* const* d_in, const int* in_sizes, int n_in,
                              void* d_out, int out_size, void* d_ws, size_t ws_size,
                              hipStream_t stream)
{
    const float* Q1 = (const float*)d_in[0];
    const float* Q2 = (const float*)d_in[1];
    const float* P  = (const float*)d_in[2];
    const float* bu = (const float*)d_in[3];
    const float* bi = (const float*)d_in[4];
    const int* items = (const int*)d_in[5];
    const int* segs  = (const int*)d_in[6];
    const int nnz = in_sizes[5];

    unsigned short* Pbf  = (unsigned short*)d_ws;            // 2 MB
    unsigned short* Q1bf = Pbf + U_CNT * DIM;                // 1 MB
    int* bounds = (int*)(Q1bf + I_CNT * DIM);                // 64 KB + 4 B

    int boundsBlocks = (nnz + 255) / 256;
    prep_kernel<<<2048 + boundsBlocks, 256, 0, stream>>>(Q1, Q1bf, segs, nnz, bounds);
    pfull_kernel<<<U_CNT, 256, 0, stream>>>(Q2, P, items, bounds, Pbf);
    // 32 groups x 32 members = 1024 blocks; each block sweeps NSTEP=32 bands.
    gemm_sig_kernel<<<32 * 32, 256, 0, stream>>>(Pbf, Q1bf, bu, bi, (float*)d_out);
}

// Round 12
// 121.901 us; speedup vs baseline: 1.2551x; 1.0921x over previous
//
#include <hip/hip_runtime.h>

#define U_CNT 16384
#define I_CNT 8192
#define DIM 64
#define BAND 16                   // rows per band (per block per step)
#define CHUNK 256                 // cols owned by one block (fixed)
#define NSTEP 32                  // bands per group sweep
#define LDS_STRIDE 68             // floats; 68 % 32 == 4 -> 2-way conflicts only (free)
#define NEG_LOG2E (-1.4426950408889634f)

typedef __bf16 bf16x8 __attribute__((ext_vector_type(8)));
typedef float f32x4 __attribute__((ext_vector_type(4)));
typedef unsigned short ushort4v __attribute__((ext_vector_type(4)));

__device__ __forceinline__ unsigned short f32_to_bf16_rtn(float f) {
    unsigned int b = __float_as_uint(f);
    b += 0x7fffu + ((b >> 16) & 1u);
    return (unsigned short)(b >> 16);
}

// Prep: blocks [0, 2048) convert Q1 -> bf16; blocks [2048, ...) scan seg_ids
// for segment boundaries (every user has >=1 item -> every bounds[u] written
// exactly once; bounds[U_CNT] = nnz). UNCHANGED from champion.
__global__ __launch_bounds__(256) void prep_kernel(
    const float* __restrict__ Q1, unsigned short* __restrict__ Q1bf,
    const int* __restrict__ segs, int nnz, int* __restrict__ bounds)
{
    if (blockIdx.x < 2048) {
        int i = blockIdx.x * 256 + threadIdx.x;   // covers I_CNT*DIM = 524288
        Q1bf[i] = f32_to_bf16_rtn(Q1[i]);
    } else {
        int i = (blockIdx.x - 2048) * 256 + threadIdx.x;
        if (i >= nnz) return;
        if (i == 0) bounds[segs[0]] = 0;
        else if (segs[i] != segs[i - 1]) bounds[segs[i]] = i;
        if (i == nnz - 1) bounds[U_CNT] = nnz;
    }
}

// One wave per user, QUARTER-WAVE PER ITEM (vectorized 4x vs champion):
// lane l loads a 16B f32x4 of row items[j + (l>>4)], covering dims
// 4*(l&15)..+3; groups stride 4 items. 4x fewer memory instructions at
// identical L2 traffic; dual accumulators for ILP. Cross-group reduce via
// 8 shfl_xor; lanes 0-15 finalize (rsqrt, +P, bf16) with an 8B ushort4
// store (128B/user contiguous).
__global__ __launch_bounds__(256) void pfull_kernel(
    const float* __restrict__ Q2, const float* __restrict__ P,
    const int* __restrict__ items, const int* __restrict__ bounds,
    unsigned short* __restrict__ Pbf)
{
    const int u = (blockIdx.x * 256 + threadIdx.x) >> 6;
    const int lane = threadIdx.x & 63;
    if (u >= U_CNT) return;
    const int qg = lane >> 4;       // quarter-group: which item in a 4-pack
    const int ql = lane & 15;       // dim slot: 16 lanes x f32x4 = 64 dims

    const int start = bounds[u];
    const int end   = bounds[u + 1];
    const int cnt   = end - start;  // guaranteed >= 1

    f32x4 acc0 = {0.f, 0.f, 0.f, 0.f}, acc1 = {0.f, 0.f, 0.f, 0.f};
    int j = start + qg;
    for (; j + 4 < end; j += 8) {
        int i0 = items[j], i1 = items[j + 4];
        f32x4 v0 = *reinterpret_cast<const f32x4*>(&Q2[i0 * DIM + ql * 4]);
        f32x4 v1 = *reinterpret_cast<const f32x4*>(&Q2[i1 * DIM + ql * 4]);
        acc0 += v0;
        acc1 += v1;
    }
    if (j < end)
        acc0 += *reinterpret_cast<const f32x4*>(&Q2[items[j] * DIM + ql * 4]);
    f32x4 acc = acc0 + acc1;

    // Reduce across the 4 quarter-groups (lanes l, l+16, l+32, l+48).
#pragma unroll
    for (int e = 0; e < 4; ++e) {
        acc[e] += __shfl_xor(acc[e], 16, 64);
        acc[e] += __shfl_xor(acc[e], 32, 64);
    }

    if (qg == 0) {
        f32x4 pv = *reinterpret_cast<const f32x4*>(&P[u * DIM + ql * 4]);
        float rs = rsqrtf((float)cnt);
        ushort4v o;
#pragma unroll
        for (int e = 0; e < 4; ++e)
            o[e] = f32_to_bf16_rtn(acc[e] * rs + pv[e]);
        *reinterpret_cast<ushort4v*>(&Pbf[u * DIM + ql * 4]) = o;
    }
}

// Coordinated-window GEMM + sigmoid — EXACT 130.6us champion (round 9).
// Grid = 1024 blocks (32 groups x 32 members). Block b: member = b&31 owns
// fixed cols [member*256, +256); group = b>>5. Step s: band (group + s*32).
// At step s the whole GPU writes rows [s*512, +512) = a contiguous 16 MB
// window sweeping linearly (fill-kernel shape) instead of 16K scattered
// 1KB-granule streams over 536 MB. B fragments + bi register-resident
// (loaded once from bf16 Q1bf); per step only the 2-instr A fragment + bu
// reload. Epilogue: sigmoid in acc layout, per-wave-private LDS transpose,
// 4 nontemporal 256B-per-row store instructions.
__global__ __launch_bounds__(256) void gemm_sig_kernel(
    const unsigned short* __restrict__ Abf, const unsigned short* __restrict__ Bbf,
    const float* __restrict__ bu, const float* __restrict__ bi,
    float* __restrict__ out)
{
    const int lane = threadIdx.x & 63;
    const int wid  = threadIdx.x >> 6;      // 0..3: 64-col sub-band within chunk
    const int r = lane & 15, g = lane >> 4;
    const int member = blockIdx.x & 31;     // fixed col chunk
    const int group  = blockIdx.x >> 5;     // 0..31
    const int col0 = member * CHUNK + wid * 64;

    __shared__ float lds_all[4][BAND * LDS_STRIDE];
    float* lds = lds_all[wid];              // per-wave private region

    // B fragments + bi: loaded ONCE, register-resident for the whole kernel.
    bf16x8 b[4][2];
    float bi_f[4];
#pragma unroll
    for (int nf = 0; nf < 4; ++nf) {
        bi_f[nf] = bi[col0 + nf * 16 + r] + 0.05f;   // fold the +0.05 here
#pragma unroll
        for (int ks = 0; ks < 2; ++ks)
            b[nf][ks] = *reinterpret_cast<const bf16x8*>(
                &Bbf[(col0 + nf * 16 + r) * DIM + ks * 32 + g * 8]);
    }

    for (int s = 0; s < NSTEP; ++s) {
        const int band = (group + s * 32) * BAND;

        // A fragment for this band (rows band..band+15), both K-steps.
        bf16x8 a[2];
#pragma unroll
        for (int ks = 0; ks < 2; ++ks)
            a[ks] = *reinterpret_cast<const bf16x8*>(
                &Abf[(band + r) * DIM + ks * 32 + g * 8]);

        float bu_g[4];
#pragma unroll
        for (int j = 0; j < 4; ++j) bu_g[j] = bu[band + g * 4 + j];

        f32x4 acc[4] = {};
#pragma unroll
        for (int ks = 0; ks < 2; ++ks)
#pragma unroll
            for (int nf = 0; nf < 4; ++nf)
                acc[nf] = __builtin_amdgcn_mfma_f32_16x16x32_bf16(
                    a[ks], b[nf][ks], acc[nf], 0, 0, 0);

        // Sigmoid in acc layout (row = g*4+j, col = nf*16+r), then transpose
        // through per-wave LDS.
#pragma unroll
        for (int nf = 0; nf < 4; ++nf)
#pragma unroll
            for (int j = 0; j < 4; ++j) {
                float x = (acc[nf][j] + bu_g[j] + bi_f[nf]) * NEG_LOG2E;
                float e = __builtin_amdgcn_exp2f(x);
                float v = 5.f * __builtin_amdgcn_rcpf(1.f + e);
                lds[(g * 4 + j) * LDS_STRIDE + nf * 16 + r] = v;
            }

        // Store: instr i covers rows i*4..i*4+3 (g picks row, r picks 16B
        // slot): 256B contiguous per row, full cache lines, nontemporal.
#pragma unroll
        for (int i = 0; i < 4; ++i) {
            const int row = i * 4 + g;
            f32x4 v = *reinterpret_cast<const f32x4*>(&lds[row * LDS_STRIDE + r * 4]);
            __builtin_nontemporal_store(v, reinterpret_cast<f32x4*>(
                &out[(size_t)(band + row) * I_CNT + col0 + r * 4]));
        }
    }
}

extern "C" void kernel_launch(void* const* d_in, const int* in_sizes, int n_in,
                              void* d_out, int out_size, void* d_ws, size_t ws_size,
                              hipStream_t stream)
{
    const float* Q1 = (const float*)d_in[0];
    const float* Q2 = (const float*)d_in[1];
    const float* P  = (const float*)d_in[2];
    const float* bu = (const float*)d_in[3];
    const float* bi = (const float*)d_in[4];
    const int* items = (const int*)d_in[5];
    const int* segs  = (const int*)d_in[6];
    const int nnz = in_sizes[5];

    unsigned short* Pbf  = (unsigned short*)d_ws;            // 2 MB
    unsigned short* Q1bf = Pbf + U_CNT * DIM;                // 1 MB
    int* bounds = (int*)(Q1bf + I_CNT * DIM);                // 64 KB + 4 B

    int boundsBlocks = (nnz + 255) / 256;
    prep_kernel<<<2048 + boundsBlocks, 256, 0, stream>>>(Q1, Q1bf, segs, nnz, bounds);
    pfull_kernel<<<U_CNT / 4, 256, 0, stream>>>(Q2, P, items, bounds, Pbf);
    // 32 groups x 32 members = 1024 blocks; each block sweeps NSTEP=32 bands.
    gemm_sig_kernel<<<32 * 32, 256, 0, stream>>>(Pbf, Q1bf, bu, bi, (float*)d_out);
}